// Round 6
// baseline (466.776 us; speedup 1.0000x reference)
//
#include <hip/hip_runtime.h>
#include <hip/hip_bf16.h>

#define N_NODES 100000
#define D 128
#define EPT 250000
#define NT 7
#define NSEG (NT * N_NODES)   // 700000
#define TOTE (NT * EPT)       // 1750000

#define SCAN_B 256
#define SCAN_IPT 4
#define SCAN_CHUNK (SCAN_B * SCAN_IPT)                    // 1024
#define SCAN_NBLK ((NSEG + SCAN_CHUNK - 1) / SCAN_CHUNK)  // 684

#define CVX_BLOCKS 12500   // 3,200,000 float4 / 256 (exact)
#define CVW_BLOCKS 512     // 131,072 / 256 (exact)
#define CNT_BLOCKS 977     // ceil(250000/256)

typedef __attribute__((ext_vector_type(8))) short bf16x8;
typedef __attribute__((ext_vector_type(4))) float f32x4;

__device__ inline float b2f(unsigned int u16) {
    union { unsigned int i; float f; } v; v.i = u16 << 16; return v.f;
}
__device__ inline unsigned short f2b(float f) {
    union { float f; unsigned int i; } v; v.f = f;
    unsigned int r = v.i + 0x7fffu + ((v.i >> 16) & 1u);
    return (unsigned short)(r >> 16);
}
__device__ inline unsigned int pack2(float a, float b) {
    return (unsigned int)f2b(a) | ((unsigned int)f2b(b) << 16);
}

struct EPtrs { const int* e[NT]; };

// ---------------- merged prep: convert_x | convert_w | count_all ----------------

__global__ __launch_bounds__(256) void prep(const float4* __restrict__ x, uint2* __restrict__ xb,
                                            const float* __restrict__ W, unsigned short* __restrict__ WbT,
                                            EPtrs ep, int* __restrict__ cnt) {
    int b = blockIdx.x, tid = threadIdx.x;
    if (b < CVX_BLOCKS) {
        int i = b * 256 + tid;               // < 3,200,000 exact
        float4 v = x[i];
        xb[i] = make_uint2(pack2(v.x, v.y), pack2(v.z, v.w));
    } else if (b < CVX_BLOCKS + CVW_BLOCKS) {
        int i = (b - CVX_BLOCKS) * 256 + tid;  // < 131072 exact
        int c = i >> 10, tk = i & 1023;
        WbT[i] = f2b(W[tk * 128 + c] * 0.125f);  // fold /8 (exact pow2)
    } else {
        int r = b - CVX_BLOCKS - CVW_BLOCKS;
        int t = r / CNT_BLOCKS;
        int i = (r % CNT_BLOCKS) * 256 + tid;
        if (i < EPT) atomicAdd(&cnt[t * N_NODES + ep.e[t][EPT + i]], 1);
    }
}

// ---------------- CSR scan ----------------

__global__ void scan_partials(const int* __restrict__ cnt, int* __restrict__ partials) {
    __shared__ int wsum[4];
    int tid = threadIdx.x;
    int base = blockIdx.x * SCAN_CHUNK + tid * SCAN_IPT;
    int s = 0;
#pragma unroll
    for (int j = 0; j < SCAN_IPT; ++j) {
        int idx = base + j;
        if (idx < NSEG) s += cnt[idx];
    }
    for (int off = 32; off > 0; off >>= 1) s += __shfl_down(s, off);
    if ((tid & 63) == 0) wsum[tid >> 6] = s;
    __syncthreads();
    if (tid == 0) partials[blockIdx.x] = wsum[0] + wsum[1] + wsum[2] + wsum[3];
}

// scan_write with inlined prefix over partials (removes scan_block dispatch)
__global__ void scan_write(const int* __restrict__ cnt, const int* __restrict__ partials,
                           int* __restrict__ scanbuf, int* __restrict__ cursor) {
    __shared__ int wsumA[4];
    __shared__ int wsum[4];
    __shared__ int basesh;
    int tid = threadIdx.x;
    int lane = tid & 63, wid = tid >> 6;

    // prefix of partials over blocks < blockIdx.x (684 ints max — trivial)
    int pre = 0;
    for (int j = tid; j < blockIdx.x; j += SCAN_B) pre += partials[j];
    for (int off = 32; off > 0; off >>= 1) pre += __shfl_down(pre, off);
    if (lane == 0) wsumA[wid] = pre;
    __syncthreads();
    if (tid == 0) basesh = wsumA[0] + wsumA[1] + wsumA[2] + wsumA[3];

    int base = blockIdx.x * SCAN_CHUNK + tid * SCAN_IPT;
    int v[SCAN_IPT];
    int tsum = 0;
#pragma unroll
    for (int j = 0; j < SCAN_IPT; ++j) {
        int idx = base + j;
        v[j] = (idx < NSEG) ? cnt[idx] : 0;
        tsum += v[j];
    }
    int inc = tsum;
    for (int d = 1; d < 64; d <<= 1) {
        int o = __shfl_up(inc, d);
        if (lane >= d) inc += o;
    }
    if (lane == 63) wsum[wid] = inc;
    __syncthreads();
    int woff = 0;
    for (int w = 0; w < wid; ++w) woff += wsum[w];
    int exc = woff + inc - tsum + basesh;
#pragma unroll
    for (int j = 0; j < SCAN_IPT; ++j) {
        int idx = base + j;
        if (idx < NSEG) { scanbuf[idx] = exc; cursor[idx] = exc; }
        exc += v[j];
    }
}

__global__ void fill_all(EPtrs ep, int* __restrict__ cursor, int* __restrict__ esrc) {
    int i = blockIdx.x * blockDim.x + threadIdx.x;
    int t = blockIdx.y;
    if (i < EPT) {
        int src = ep.e[t][i];
        int dst = ep.e[t][EPT + i];
        int pos = atomicAdd(&cursor[t * N_NODES + dst], 1);
        esrc[pos] = src;
    }
}

// ---------------- fused aggregate + GEMM ----------------
// block = 512 threads (8 waves), tile = 32 nodes, LDS 64 KB -> 2 blocks/CU.
// Lane mapping: nloc = tid>>4 (node), chunk = tid&15 (16B column chunk).
// A 16-lane group reads one x-row as 16 contiguous 16B chunks -> one wave
// load = 4 full rows (1 KB). Sweep A: branchless first-4 edges of all 7
// types (~35 independent loads in flight). Sweep B: c>4 extensions (11%).
// Sweep C: write type means + in-register global mean. Phase 2: MFMA.

__device__ inline uint4 ldrow(const unsigned short* __restrict__ xb, int idx, int chunk) {
    return *(const uint4*)(xb + (size_t)idx * 128 + chunk * 8);
}

__device__ inline void acc8(float (&s)[8], uint4 v, bool p) {
    s[0] += p ? b2f(v.x & 0xffffu) : 0.f;
    s[1] += p ? b2f(v.x >> 16) : 0.f;
    s[2] += p ? b2f(v.y & 0xffffu) : 0.f;
    s[3] += p ? b2f(v.y >> 16) : 0.f;
    s[4] += p ? b2f(v.z & 0xffffu) : 0.f;
    s[5] += p ? b2f(v.z >> 16) : 0.f;
    s[6] += p ? b2f(v.w & 0xffffu) : 0.f;
    s[7] += p ? b2f(v.w >> 16) : 0.f;
}

__global__ __launch_bounds__(512, 4) void fused_agg_gemm(const unsigned short* __restrict__ xb,
                                                         const int* __restrict__ scanbuf,
                                                         const int* __restrict__ cnt,
                                                         const int* __restrict__ esrc,
                                                         const unsigned short* __restrict__ WbT,
                                                         float* __restrict__ out) {
    __shared__ char lds[32 * 2048];  // 64 KB: [32 rows][1024 bf16], XOR-swizzled

    int tid = threadIdx.x;
    int lane = tid & 63;
    int nloc = tid >> 4;       // 0..31
    int chunk = tid & 15;      // 0..15
    int tile0 = blockIdx.x * 32;
    int n = tile0 + nloc;

    // preload all segment descriptors (independent loads, issued up front)
    int st[NT], ct[NT];
#pragma unroll
    for (int t = 0; t < NT; ++t) {
        st[t] = scanbuf[t * N_NODES + n];
        ct[t] = cnt[t * N_NODES + n];
    }

    float su[NT][8];

    // ---- sweep A: first 4 edges of every type, branchless ----
#pragma unroll
    for (int t = 0; t < NT; ++t) {
        int c = ct[t];
        int4 h = *(const int4*)(esrc + st[t]);  // padded tail -> always safe
        int i0 = (c > 0) ? h.x : 0;
        int i1 = (c > 1) ? h.y : i0;
        int i2 = (c > 2) ? h.z : i0;
        int i3 = (c > 3) ? h.w : i0;
        uint4 v0 = ldrow(xb, i0, chunk);
        uint4 v1 = ldrow(xb, i1, chunk);
        uint4 v2 = ldrow(xb, i2, chunk);
        uint4 v3 = ldrow(xb, i3, chunk);
#pragma unroll
        for (int i = 0; i < 8; ++i) su[t][i] = 0.f;
        acc8(su[t], v0, c > 0);
        acc8(su[t], v1, c > 1);
        acc8(su[t], v2, c > 2);
        acc8(su[t], v3, c > 3);
    }

    // ---- sweep B: extensions for c > 4 (P ~ 11%) ----
#pragma unroll
    for (int t = 0; t < NT; ++t) {
        int c = ct[t];
        if (c > 4) {
            int s = st[t];
            int4 h = *(const int4*)(esrc + s + 4);
            int i5 = (c > 5) ? h.y : h.x;
            int i6 = (c > 6) ? h.z : h.x;
            int i7 = (c > 7) ? h.w : h.x;
            uint4 v4 = ldrow(xb, h.x, chunk);
            uint4 v5 = ldrow(xb, i5, chunk);
            uint4 v6 = ldrow(xb, i6, chunk);
            uint4 v7 = ldrow(xb, i7, chunk);
            acc8(su[t], v4, true);
            acc8(su[t], v5, c > 5);
            acc8(su[t], v6, c > 6);
            acc8(su[t], v7, c > 7);
            for (int j = 8; j < c; ++j) {  // P ~ 0.2%
                uint4 v = ldrow(xb, esrc[s + j], chunk);
                acc8(su[t], v, true);
            }
        }
    }

    // ---- sweep C: write type means + global mean ----
    char* rowp = lds + nloc * 2048;
    int rsw = (nloc & 7) << 4;
    float g[8];
#pragma unroll
    for (int i = 0; i < 8; ++i) g[i] = 0.f;
    int ctot = 0;
#pragma unroll
    for (int t = 0; t < NT; ++t) {
        int c = ct[t];
        ctot += c;
        float inv = 1.0f / (float)(c > 0 ? c : 1);
        uint4 pk;
        pk.x = pack2(su[t][0] * inv, su[t][1] * inv);
        pk.y = pack2(su[t][2] * inv, su[t][3] * inv);
        pk.z = pack2(su[t][4] * inv, su[t][5] * inv);
        pk.w = pack2(su[t][6] * inv, su[t][7] * inv);
        *(uint4*)(rowp + ((t * 256 + chunk * 16) ^ rsw)) = pk;
#pragma unroll
        for (int i = 0; i < 8; ++i) g[i] += su[t][i];
    }
    float gi = 1.0f / (float)(ctot > 0 ? ctot : 1);
    uint4 pg;
    pg.x = pack2(g[0] * gi, g[1] * gi);
    pg.y = pack2(g[2] * gi, g[3] * gi);
    pg.z = pack2(g[4] * gi, g[5] * gi);
    pg.w = pack2(g[6] * gi, g[7] * gi);
    *(uint4*)(rowp + ((NT * 256 + chunk * 16) ^ rsw)) = pg;

    __syncthreads();

    // ---- phase 2: GEMM [32][1024] @ WbT -> out[32][128] ----
    int wvu = __builtin_amdgcn_readfirstlane(tid >> 6);
    int lr = lane & 15, lk = lane >> 4;
    f32x4 acc0 = (f32x4){0.f, 0.f, 0.f, 0.f};
    f32x4 acc1 = (f32x4){0.f, 0.f, 0.f, 0.f};
    const unsigned short* wb = WbT + (size_t)(wvu * 16 + lr) * 1024;
    int rx = (lr & 7) << 4;  // rows r and r+16 share (r&7) -> same XOR

#pragma unroll 4
    for (int k0 = 0; k0 < 1024; k0 += 32) {
        int koff = (k0 + lk * 8) * 2;
        bf16x8 fa0 = *(const bf16x8*)(lds + ((lr * 2048 + koff) ^ rx));
        bf16x8 fa1 = *(const bf16x8*)(lds + (((lr + 16) * 2048 + koff) ^ rx));
        bf16x8 fb = *(const bf16x8*)(wb + k0 + lk * 8);
        acc0 = __builtin_amdgcn_mfma_f32_16x16x32_bf16(fa0, fb, acc0, 0, 0, 0);
        acc1 = __builtin_amdgcn_mfma_f32_16x16x32_bf16(fa1, fb, acc1, 0, 0, 0);
    }

    int col = wvu * 16 + lr;
    int n0 = tile0 + lk * 4;
#pragma unroll
    for (int qq = 0; qq < 4; ++qq) {
        out[(size_t)(n0 + qq) * 128 + col] = acc0[qq];
        out[(size_t)(n0 + 16 + qq) * 128 + col] = acc1[qq];
    }
}

// ---------------- launch ----------------

extern "C" void kernel_launch(void* const* d_in, const int* in_sizes, int n_in,
                              void* d_out, int out_size, void* d_ws, size_t ws_size,
                              hipStream_t stream) {
    const float* x = (const float*)d_in[0];
    const float* W = (const float*)d_in[1];
    EPtrs ep;
    for (int t = 0; t < NT; ++t) ep.e[t] = (const int*)d_in[2 + t];
    float* out = (float*)d_out;

    char* ws = (char*)d_ws;
    int* cnt            = (int*)(ws + 0);                    // 2,800,000
    int* scanbuf        = (int*)(ws + 2800000);              // 2,800,000
    int* cursor         = (int*)(ws + 5600000);              // 2,800,000
    int* partials       = (int*)(ws + 8400000);              // 4,096
    unsigned short* WbT = (unsigned short*)(ws + 8404096);   // 262,144
    int* esrc           = (int*)(ws + 8666240);              // 7,000,000 + 192 pad
    unsigned short* xb  = (unsigned short*)(ws + 15666432);  // 25,600,000

    hipMemsetAsync(cnt, 0, NSEG * sizeof(int), stream);

    int prep_blocks = CVX_BLOCKS + CVW_BLOCKS + CNT_BLOCKS * NT;  // 19851
    prep<<<prep_blocks, 256, 0, stream>>>((const float4*)x, (uint2*)xb, W, WbT, ep, cnt);

    scan_partials<<<SCAN_NBLK, SCAN_B, 0, stream>>>(cnt, partials);
    scan_write<<<SCAN_NBLK, SCAN_B, 0, stream>>>(cnt, partials, scanbuf, cursor);

    dim3 egrid(CNT_BLOCKS, NT);
    fill_all<<<egrid, 256, 0, stream>>>(ep, cursor, esrc);

    int nblocks = N_NODES / 32;  // 3125, exact
    fused_agg_gemm<<<nblocks, 512, 0, stream>>>(xb, scanbuf, cnt, esrc, WbT, out);
}

// Round 7
// 371.153 us; speedup vs baseline: 1.2576x; 1.2576x over previous
//
#include <hip/hip_runtime.h>
#include <hip/hip_bf16.h>

#define N_NODES 100000
#define D 128
#define EPT 250000
#define NT 7
#define NSEG (NT * N_NODES)   // 700000
#define TOTE (NT * EPT)       // 1750000
#define ZROW N_NODES          // index of the all-zero row appended to xb

#define SCAN_B 256
#define SCAN_IPT 4
#define SCAN_CHUNK (SCAN_B * SCAN_IPT)                    // 1024
#define SCAN_NBLK ((NSEG + SCAN_CHUNK - 1) / SCAN_CHUNK)  // 684

#define CVX_BLOCKS 12500   // 3,200,000 float4 / 256 (exact)
#define CVW_BLOCKS 512     // 131,072 / 256 (exact)
#define CNT_BLOCKS 977     // ceil(250000/256)

typedef __attribute__((ext_vector_type(8))) short bf16x8;
typedef __attribute__((ext_vector_type(4))) float f32x4;

__device__ inline float b2f(unsigned int u16) {
    union { unsigned int i; float f; } v; v.i = u16 << 16; return v.f;
}
__device__ inline unsigned short f2b(float f) {
    union { float f; unsigned int i; } v; v.f = f;
    unsigned int r = v.i + 0x7fffu + ((v.i >> 16) & 1u);
    return (unsigned short)(r >> 16);
}
__device__ inline unsigned int pack2(float a, float b) {
    return (unsigned int)f2b(a) | ((unsigned int)f2b(b) << 16);
}

struct EPtrs { const int* e[NT]; };

// ---------------- merged prep: convert_x | zero-row | convert_w | count_all ----------------

__global__ __launch_bounds__(256) void prep(const float4* __restrict__ x, uint2* __restrict__ xb,
                                            const float* __restrict__ W, unsigned short* __restrict__ WbT,
                                            EPtrs ep, int* __restrict__ cnt) {
    int b = blockIdx.x, tid = threadIdx.x;
    if (b < CVX_BLOCKS) {
        int i = b * 256 + tid;               // < 3,200,000 exact
        float4 v = x[i];
        xb[i] = make_uint2(pack2(v.x, v.y), pack2(v.z, v.w));
    } else if (b == CVX_BLOCKS) {
        if (tid < 16) ((uint4*)xb)[(size_t)ZROW * 16 + tid] = make_uint4(0u, 0u, 0u, 0u);
    } else if (b < CVX_BLOCKS + 1 + CVW_BLOCKS) {
        int i = (b - CVX_BLOCKS - 1) * 256 + tid;  // < 131072 exact
        int c = i >> 10, tk = i & 1023;
        WbT[i] = f2b(W[tk * 128 + c] * 0.125f);  // fold /8 (exact pow2)
    } else {
        int r = b - CVX_BLOCKS - 1 - CVW_BLOCKS;
        int t = r / CNT_BLOCKS;
        int i = (r % CNT_BLOCKS) * 256 + tid;
        if (i < EPT) atomicAdd(&cnt[t * N_NODES + ep.e[t][EPT + i]], 1);
    }
}

// ---------------- CSR scan ----------------

__global__ void scan_partials(const int* __restrict__ cnt, int* __restrict__ partials) {
    __shared__ int wsum[4];
    int tid = threadIdx.x;
    int base = blockIdx.x * SCAN_CHUNK + tid * SCAN_IPT;
    int s = 0;
#pragma unroll
    for (int j = 0; j < SCAN_IPT; ++j) {
        int idx = base + j;
        if (idx < NSEG) s += cnt[idx];
    }
    for (int off = 32; off > 0; off >>= 1) s += __shfl_down(s, off);
    if ((tid & 63) == 0) wsum[tid >> 6] = s;
    __syncthreads();
    if (tid == 0) partials[blockIdx.x] = wsum[0] + wsum[1] + wsum[2] + wsum[3];
}

// scan_write with inlined prefix over partials; writes cursor only
__global__ void scan_write(const int* __restrict__ cnt, const int* __restrict__ partials,
                           int* __restrict__ cursor) {
    __shared__ int wsumA[4];
    __shared__ int wsum[4];
    __shared__ int basesh;
    int tid = threadIdx.x;
    int lane = tid & 63, wid = tid >> 6;

    int pre = 0;
    for (int j = tid; j < blockIdx.x; j += SCAN_B) pre += partials[j];
    for (int off = 32; off > 0; off >>= 1) pre += __shfl_down(pre, off);
    if (lane == 0) wsumA[wid] = pre;
    __syncthreads();
    if (tid == 0) basesh = wsumA[0] + wsumA[1] + wsumA[2] + wsumA[3];

    int base = blockIdx.x * SCAN_CHUNK + tid * SCAN_IPT;
    int v[SCAN_IPT];
    int tsum = 0;
#pragma unroll
    for (int j = 0; j < SCAN_IPT; ++j) {
        int idx = base + j;
        v[j] = (idx < NSEG) ? cnt[idx] : 0;
        tsum += v[j];
    }
    int inc = tsum;
    for (int d = 1; d < 64; d <<= 1) {
        int o = __shfl_up(inc, d);
        if (lane >= d) inc += o;
    }
    if (lane == 63) wsum[wid] = inc;
    __syncthreads();
    int woff = 0;
    for (int w = 0; w < wid; ++w) woff += wsum[w];
    int exc = woff + inc - tsum + basesh;
#pragma unroll
    for (int j = 0; j < SCAN_IPT; ++j) {
        int idx = base + j;
        if (idx < NSEG) cursor[idx] = exc;
        exc += v[j];
    }
}

__global__ void fill_all(EPtrs ep, int* __restrict__ cursor, int* __restrict__ esrc) {
    int i = blockIdx.x * blockDim.x + threadIdx.x;
    int t = blockIdx.y;
    if (i < EPT) {
        int src = ep.e[t][i];
        int dst = ep.e[t][EPT + i];
        int pos = atomicAdd(&cursor[t * N_NODES + dst], 1);
        esrc[pos] = src;
    }
}

// ---------------- fused aggregate + GEMM ----------------
// block = 512 threads (8 waves), tile = 32 nodes, LDS 64 KB -> 2 blocks/CU.
// Lane mapping: nloc = tid>>4 (node), chunk = tid&15 (16B column chunk); a
// 16-lane group reads one x-row as 16 contiguous 16B chunks (1KB per wave
// load). Types processed in PAIRS with statically-indexed float s[8] accs
// (no runtime-indexed arrays -> no scratch). Unused gather slots clamp to a
// zero row (no per-element predication). cursor holds segment ENDS after
// fill_all; start = end - cnt.

__device__ __forceinline__ uint4 ldrow(const unsigned short* __restrict__ xb, int idx, int chunk) {
    return *(const uint4*)(xb + (size_t)idx * 128 + chunk * 8);
}

__device__ __forceinline__ void accrow(float (&s)[8], uint4 v) {
    s[0] += b2f(v.x & 0xffffu);  s[1] += b2f(v.x >> 16);
    s[2] += b2f(v.y & 0xffffu);  s[3] += b2f(v.y >> 16);
    s[4] += b2f(v.z & 0xffffu);  s[5] += b2f(v.z >> 16);
    s[6] += b2f(v.w & 0xffffu);  s[7] += b2f(v.w >> 16);
}

__device__ __forceinline__ void main4(const unsigned short* __restrict__ xb, int4 h, int c,
                                      int chunk, float (&s)[8]) {
    int i0 = (c > 0) ? h.x : ZROW;
    int i1 = (c > 1) ? h.y : ZROW;
    int i2 = (c > 2) ? h.z : ZROW;
    int i3 = (c > 3) ? h.w : ZROW;
    uint4 v0 = ldrow(xb, i0, chunk);
    uint4 v1 = ldrow(xb, i1, chunk);
    uint4 v2 = ldrow(xb, i2, chunk);
    uint4 v3 = ldrow(xb, i3, chunk);
    accrow(s, v0); accrow(s, v1); accrow(s, v2); accrow(s, v3);
}

__device__ __forceinline__ void tail4(const unsigned short* __restrict__ xb,
                                      const int* __restrict__ esrc, int start, int c,
                                      int chunk, float (&s)[8]) {
    if (c > 4) {
        int4 h = *(const int4*)(esrc + start + 4);
        int i5 = (c > 5) ? h.y : ZROW;
        int i6 = (c > 6) ? h.z : ZROW;
        int i7 = (c > 7) ? h.w : ZROW;
        uint4 v4 = ldrow(xb, h.x, chunk);
        uint4 v5 = ldrow(xb, i5, chunk);
        uint4 v6 = ldrow(xb, i6, chunk);
        uint4 v7 = ldrow(xb, i7, chunk);
        accrow(s, v4); accrow(s, v5); accrow(s, v6); accrow(s, v7);
        for (int j = 8; j < c; ++j) {  // P ~ 0.2%
            uint4 v = ldrow(xb, esrc[start + j], chunk);
            accrow(s, v);
        }
    }
}

__global__ __launch_bounds__(512, 4) void fused_agg_gemm(const unsigned short* __restrict__ xb,
                                                         const int* __restrict__ cursor,
                                                         const int* __restrict__ cnt,
                                                         const int* __restrict__ esrc,
                                                         const unsigned short* __restrict__ WbT,
                                                         float* __restrict__ out) {
    __shared__ char lds[32 * 2048];  // 64 KB: [32 rows][1024 bf16], XOR-swizzled

    int tid = threadIdx.x;
    int lane = tid & 63;
    int nloc = tid >> 4;       // 0..31
    int chunk = tid & 15;      // 0..15
    int tile0 = blockIdx.x * 32;
    int n = tile0 + nloc;

    // descriptors: start = end - cnt (cursor holds ends after fill_all)
    int st[NT], ct[NT];
#pragma unroll
    for (int t = 0; t < NT; ++t) {
        int e = cursor[t * N_NODES + n];
        int c = cnt[t * N_NODES + n];
        ct[t] = c;
        st[t] = e - c;
    }
    // heads: all 7 int4s issued up front (independent)
    int4 hh[NT];
#pragma unroll
    for (int t = 0; t < NT; ++t) hh[t] = *(const int4*)(esrc + st[t]);

    char* rowp = lds + nloc * 2048;
    int rsw = (nloc & 7) << 4;
    float g[8] = {0.f, 0.f, 0.f, 0.f, 0.f, 0.f, 0.f, 0.f};
    int ctot = 0;
    float sa[8], sb[8];

#define EMIT(T, S)                                                            \
    {                                                                         \
        int c_ = ct[T];                                                       \
        ctot += c_;                                                           \
        float inv_ = 1.0f / (float)(c_ > 0 ? c_ : 1);                         \
        uint4 pk_;                                                            \
        pk_.x = pack2(S[0] * inv_, S[1] * inv_);                              \
        pk_.y = pack2(S[2] * inv_, S[3] * inv_);                              \
        pk_.z = pack2(S[4] * inv_, S[5] * inv_);                              \
        pk_.w = pack2(S[6] * inv_, S[7] * inv_);                              \
        *(uint4*)(rowp + (((T) * 256 + chunk * 16) ^ rsw)) = pk_;             \
        for (int i_ = 0; i_ < 8; ++i_) g[i_] += S[i_];                        \
    }

#define PAIR(TA, TB)                                                          \
    {                                                                         \
        for (int i_ = 0; i_ < 8; ++i_) { sa[i_] = 0.f; sb[i_] = 0.f; }        \
        main4(xb, hh[TA], ct[TA], chunk, sa);                                 \
        main4(xb, hh[TB], ct[TB], chunk, sb);                                 \
        tail4(xb, esrc, st[TA], ct[TA], chunk, sa);                           \
        tail4(xb, esrc, st[TB], ct[TB], chunk, sb);                           \
        EMIT(TA, sa); EMIT(TB, sb);                                           \
    }

    PAIR(0, 1)
    PAIR(2, 3)
    PAIR(4, 5)
    {
        for (int i_ = 0; i_ < 8; ++i_) sa[i_] = 0.f;
        main4(xb, hh[6], ct[6], chunk, sa);
        tail4(xb, esrc, st[6], ct[6], chunk, sa);
        EMIT(6, sa)
    }

    // global mean row
    float gi = 1.0f / (float)(ctot > 0 ? ctot : 1);
    uint4 pg;
    pg.x = pack2(g[0] * gi, g[1] * gi);
    pg.y = pack2(g[2] * gi, g[3] * gi);
    pg.z = pack2(g[4] * gi, g[5] * gi);
    pg.w = pack2(g[6] * gi, g[7] * gi);
    *(uint4*)(rowp + ((NT * 256 + chunk * 16) ^ rsw)) = pg;

    __syncthreads();

    // ---- phase 2: GEMM [32][1024] @ WbT -> out[32][128] ----
    int wvu = __builtin_amdgcn_readfirstlane(tid >> 6);
    int lr = lane & 15, lk = lane >> 4;
    f32x4 acc0 = (f32x4){0.f, 0.f, 0.f, 0.f};
    f32x4 acc1 = (f32x4){0.f, 0.f, 0.f, 0.f};
    const unsigned short* wb = WbT + (size_t)(wvu * 16 + lr) * 1024;
    int rx = (lr & 7) << 4;  // rows r and r+16 share (r&7) -> same XOR

#pragma unroll 4
    for (int k0 = 0; k0 < 1024; k0 += 32) {
        int koff = (k0 + lk * 8) * 2;
        bf16x8 fa0 = *(const bf16x8*)(lds + ((lr * 2048 + koff) ^ rx));
        bf16x8 fa1 = *(const bf16x8*)(lds + (((lr + 16) * 2048 + koff) ^ rx));
        bf16x8 fb = *(const bf16x8*)(wb + k0 + lk * 8);
        acc0 = __builtin_amdgcn_mfma_f32_16x16x32_bf16(fa0, fb, acc0, 0, 0, 0);
        acc1 = __builtin_amdgcn_mfma_f32_16x16x32_bf16(fa1, fb, acc1, 0, 0, 0);
    }

    int col = wvu * 16 + lr;
    int n0 = tile0 + lk * 4;
#pragma unroll
    for (int qq = 0; qq < 4; ++qq) {
        out[(size_t)(n0 + qq) * 128 + col] = acc0[qq];
        out[(size_t)(n0 + 16 + qq) * 128 + col] = acc1[qq];
    }
}

// ---------------- launch ----------------

extern "C" void kernel_launch(void* const* d_in, const int* in_sizes, int n_in,
                              void* d_out, int out_size, void* d_ws, size_t ws_size,
                              hipStream_t stream) {
    const float* x = (const float*)d_in[0];
    const float* W = (const float*)d_in[1];
    EPtrs ep;
    for (int t = 0; t < NT; ++t) ep.e[t] = (const int*)d_in[2 + t];
    float* out = (float*)d_out;

    char* ws = (char*)d_ws;
    int* cnt            = (int*)(ws + 0);                    // 2,800,000
    int* cursor         = (int*)(ws + 2800000);              // 2,800,000
    int* partials       = (int*)(ws + 5600000);              // 4,096
    unsigned short* WbT = (unsigned short*)(ws + 5604096);   // 262,144
    int* esrc           = (int*)(ws + 5866240);              // 7,000,000 + 256 pad
    unsigned short* xb  = (unsigned short*)(ws + 12866496);  // 25,600,256 (incl. zero row)

    hipMemsetAsync(cnt, 0, NSEG * sizeof(int), stream);

    int prep_blocks = CVX_BLOCKS + 1 + CVW_BLOCKS + CNT_BLOCKS * NT;  // 19852
    prep<<<prep_blocks, 256, 0, stream>>>((const float4*)x, (uint2*)xb, W, WbT, ep, cnt);

    scan_partials<<<SCAN_NBLK, SCAN_B, 0, stream>>>(cnt, partials);
    scan_write<<<SCAN_NBLK, SCAN_B, 0, stream>>>(cnt, partials, cursor);

    dim3 egrid(CNT_BLOCKS, NT);
    fill_all<<<egrid, 256, 0, stream>>>(ep, cursor, esrc);

    int nblocks = N_NODES / 32;  // 3125, exact
    fused_agg_gemm<<<nblocks, 512, 0, stream>>>(xb, cursor, cnt, esrc, WbT, out);
}